// Round 8
// baseline (2530.019 us; speedup 1.0000x reference)
//
#include <hip/hip_runtime.h>
#include <math.h>

#define NB 64      // batch
#define NP 12      // encoder steps
#define NQ 12      // decoder steps
#define NT 24      // P+Q
#define NN 325     // nodes
#define ND 64      // units
#define NR 20800   // NN*NB rows
#define CAP 64     // max nnz per S row

typedef __attribute__((ext_vector_type(8))) short frag8;
typedef __attribute__((ext_vector_type(4))) float f32x4;

__device__ inline unsigned short f2bf(float f) {
  unsigned u = __builtin_bit_cast(unsigned, f);
  unsigned r = u + 0x7FFFu + ((u >> 16) & 1u);
  return (unsigned short)(r >> 16);
}
__device__ inline float bf2f(unsigned short h) {
  unsigned u = ((unsigned)h) << 16;
  return __builtin_bit_cast(float, u);
}

__global__ void k_te(const int* __restrict__ TE, const float* __restrict__ W1,
                     const float* __restrict__ b1, const float* __restrict__ W2,
                     const float* __restrict__ b2, float* __restrict__ te) {
  int row = blockIdx.x;            // b*24+t  (1536 rows)
  int d = threadIdx.x;
  __shared__ float s[ND];
  int wd = TE[row * 2 + 0], td = TE[row * 2 + 1];
  float v = W1[wd * ND + d] + W1[(7 + td) * ND + d] + b1[d];
  s[d] = v > 0.f ? v : 0.f;
  __syncthreads();
  float acc = b2[d];
  #pragma unroll 8
  for (int k = 0; k < ND; k++) acc = fmaf(s[k], W2[k * ND + d], acc);
  te[row * ND + d] = acc;
}

__global__ void k_zero(float* __restrict__ p, int n) {
  int i = blockIdx.x * 256 + threadIdx.x;
  if (i < n) p[i] = 0.f;
}

// W (384 x nw) fp32 -> k-major bf16 hi/lo: Wh/Wl[n*384 + k]
__global__ void k_convW(const float* __restrict__ W, unsigned short* __restrict__ Wh,
                        unsigned short* __restrict__ Wl, int nw) {
  int k = blockIdx.x;              // 384
  int n = threadIdx.x;             // nw
  float w = W[k * nw + n];
  unsigned short h = f2bf(w);
  Wh[n * 384 + k] = h;
  Wl[n * 384 + k] = f2bf(w - bf2f(h));
}

// CSR build for S0/S1; one wave per (row, support), ballot compaction.
__global__ void k_csr(const float* __restrict__ S0g, const float* __restrict__ S1g,
                      int* __restrict__ cnt, int* __restrict__ idx,
                      float* __restrict__ val) {
  int m = blockIdx.x, z = blockIdx.y;
  const float* S = z ? S1g : S0g;
  int lane = threadIdx.x;
  int c = 0;
  for (int k0 = 0; k0 < NN; k0 += 64) {
    int k = k0 + lane;
    float v = (k < NN) ? S[m * NN + k] : 0.f;
    bool p = (v != 0.f);
    unsigned long long mask = __ballot(p);
    int pos = c + __popcll(mask & ((1ull << lane) - 1ull));
    if (p) {
      idx[(z * NN + m) * CAP + pos] = k;
      val[(z * NN + m) * CAP + pos] = v;
    }
    c += __popcll(mask);
  }
  if (lane == 0) cnt[z * NN + m] = c;
}

// SE[z][m][d] = sum_j val*E_se[idx[j]][d];  sumv[z][m] = sum_j val
__global__ void k_se(const int* __restrict__ cnt, const int* __restrict__ idx,
                     const float* __restrict__ val, const float* __restrict__ E_se,
                     float* __restrict__ SE, float* __restrict__ sumv) {
  int m = blockIdx.x, z = blockIdx.y, d = threadIdx.x;
  int nz = cnt[z * NN + m];
  float acc = 0.f, sv = 0.f;
  for (int j = 0; j < nz; j++) {
    float v = val[(z * NN + m) * CAP + j];
    int jn = idx[(z * NN + m) * CAP + j];
    acc = fmaf(v, E_se[jn * ND + d], acc);
    sv += v;
  }
  SE[(z * NN + m) * ND + d] = acc;
  if (d == 0) sumv[z * NN + m] = sv;
}

// embX[n*64+b][d] = (relu(X*Wi1+bi1)@Wi2+bi2)[d] for one encoder step t
__global__ void k_embX1(const float* __restrict__ X, const float* __restrict__ Wi1,
                        const float* __restrict__ bi1, const float* __restrict__ Wi2,
                        const float* __restrict__ bi2, float* __restrict__ embX, int t) {
  int row = blockIdx.x; int n = row >> 6, b = row & 63; int d = threadIdx.x;
  __shared__ float s[ND];
  float x = X[(b * NP + t) * NN + n];
  float v = fmaf(x, Wi1[d], bi1[d]);
  s[d] = v > 0.f ? v : 0.f;
  __syncthreads();
  float acc = bi2[d];
  #pragma unroll 8
  for (int k = 0; k < ND; k++) acc = fmaf(s[k], Wi2[k * ND + d], acc);
  embX[row * ND + d] = acc;
}

// 4x-grouped neighbor gather: dst = sum_j sVal[z][j] * SRC[row(j)]
// (manual grouping for MLP — 4 outstanding loads; no pragmas)
#define GATH4(dst, SRC, z) do {                                               \
  int nz_ = sCnt[z];                                                          \
  f32x4 a0_ = (f32x4)0.f, a1_ = (f32x4)0.f, a2_ = (f32x4)0.f,                 \
        a3_ = (f32x4)0.f;                                                     \
  int j_ = 0;                                                                 \
  for (; j_ + 4 <= nz_; j_ += 4) {                                            \
    float v0_ = sVal[z][j_],     v1_ = sVal[z][j_ + 1];                       \
    float v2_ = sVal[z][j_ + 2], v3_ = sVal[z][j_ + 3];                       \
    int i0_ = sIdx[z][j_],     i1_ = sIdx[z][j_ + 1];                         \
    int i2_ = sIdx[z][j_ + 2], i3_ = sIdx[z][j_ + 3];                         \
    f32x4 g0_ = *(const f32x4*)&SRC[((size_t)(i0_ * 64 + b)) * ND + ko];      \
    f32x4 g1_ = *(const f32x4*)&SRC[((size_t)(i1_ * 64 + b)) * ND + ko];      \
    f32x4 g2_ = *(const f32x4*)&SRC[((size_t)(i2_ * 64 + b)) * ND + ko];      \
    f32x4 g3_ = *(const f32x4*)&SRC[((size_t)(i3_ * 64 + b)) * ND + ko];      \
    a0_ += v0_ * g0_; a1_ += v1_ * g1_; a2_ += v2_ * g2_; a3_ += v3_ * g3_;   \
  }                                                                           \
  for (; j_ < nz_; j_++) {                                                    \
    float v_ = sVal[z][j_]; int i_ = sIdx[z][j_];                             \
    a0_ += v_ * *(const f32x4*)&SRC[((size_t)(i_ * 64 + b)) * ND + ko];       \
  }                                                                           \
  dst = (a0_ + a1_) + (a2_ + a3_);                                            \
} while (0)

// Fused gconv: per block = 16-row panel (node n, batch-quarter bq).
// XCD-aligned decode (round-robin bid%8 -> XCD): bq = (bid&7)>>1 so each
// XCD owns one batch-quarter slice of h/RH/embX (1.33 MB, L2-resident)
// and ALL gather addresses land in the local slice.
// K-split 2-phase LDS (6 slabs, 16.4 KB). x-decomposition (exact):
// S@x = sv*te + SE (+ S@embX if enc); cand recomputes it (no SVx relay).
//  MODE 0 (gate, NW=128): sg=sigmoid; c<64 -> RH=sg*h; c>=64 -> U=sg.
//  MODE 1 (cand, NW=64): h = u*h + (1-u)*tanh(acc+b).
template<int NW, int MODE>
__global__ void __launch_bounds__(256, 6)
k_fused(int t, int enc,
        const float* __restrict__ te, const float* __restrict__ E_se,
        const float* __restrict__ embX,
        float* __restrict__ h, float* __restrict__ RH, float* __restrict__ Ubuf,
        const float* __restrict__ SE, const float* __restrict__ sumv,
        const int* __restrict__ cnt, const int* __restrict__ idx,
        const float* __restrict__ val,
        const unsigned short* __restrict__ Wh, const unsigned short* __restrict__ Wl,
        const float* __restrict__ bias) {
  int bid = blockIdx.x;
  int p8 = bid & 7;                // XCD id under round-robin dispatch
  int bq = p8 >> 1;                // batch-quarter pinned per XCD pair
  int n = (bid >> 3) * 2 + (p8 & 1);
  if (n >= NN) return;
  int row0 = n * 64 + bq * 16;
  int tid = threadIdx.x;

  __shared__ unsigned short Ah[6 * 16 * 40];   // 7680 B
  __shared__ unsigned short Al[6 * 16 * 40];   // 7680 B
  __shared__ int   sIdx[2][CAP];
  __shared__ float sVal[2][CAP];
  __shared__ int   sCnt[2];

  if (tid < 128) {
    int z = tid >> 6, l = tid & 63;
    sIdx[z][l] = idx[(z * NN + n) * CAP + l];
    sVal[z][l] = val[(z * NN + n) * CAP + l];
    if (l == 0) sCnt[z] = cnt[z * NN + n];
  }
  __syncthreads();

  int r = tid >> 4, kq = tid & 15;
  int b = bq * 16 + r;
  int grow = row0 + r;
  int ko = kq * 4;

  // ---- gather all six chunks (fp32 regs) ----
  f32x4 tev = *(const f32x4*)&te[(b * NT + t) * ND + ko];
  f32x4 c0 = tev + *(const f32x4*)&E_se[n * ND + ko];
  if (enc) c0 += *(const f32x4*)&embX[(size_t)grow * ND + ko];
  f32x4 c1, c2, c3, c4, c5;
  float sv0 = sumv[n], sv1 = sumv[NN + n];
  c2 = sv0 * tev + *(const f32x4*)&SE[n * ND + ko];
  c4 = sv1 * tev + *(const f32x4*)&SE[(NN + n) * ND + ko];
  if (enc) {
    f32x4 gx;
    GATH4(gx, embX, 0); c2 += gx;
    GATH4(gx, embX, 1); c4 += gx;
  }
  if (MODE == 0) {
    c1 = *(const f32x4*)&h[(size_t)grow * ND + ko];
    GATH4(c3, h, 0);
    GATH4(c5, h, 1);
  } else {
    c1 = *(const f32x4*)&RH[(size_t)grow * ND + ko];
    GATH4(c3, RH, 0);
    GATH4(c5, RH, 1);
  }

  // CST: local slab buffer (6 slabs). Chunk cc (local 0..2) covers
  // local slab 2cc+(kq>>3), row r, within-slab k (kq&7)*4.
  int r40 = r * 40;
  int sub = (kq >> 3) * 16 * 40 + (kq & 7) * 4;
  #define CST(vec, cc) do {                                                  \
    int _off = (cc) * 2 * 16 * 40 + sub + r40;                               \
    unsigned short h0 = f2bf(vec[0]), h1 = f2bf(vec[1]),                     \
                   h2 = f2bf(vec[2]), h3 = f2bf(vec[3]);                     \
    ushort4 hv = {h0, h1, h2, h3};                                           \
    ushort4 lv = {f2bf(vec[0] - bf2f(h0)), f2bf(vec[1] - bf2f(h1)),          \
                  f2bf(vec[2] - bf2f(h2)), f2bf(vec[3] - bf2f(h3))};         \
    *(ushort4*)&Ah[_off] = hv;                                               \
    *(ushort4*)&Al[_off] = lv;                                               \
  } while (0)

  int lane = tid & 63, w = tid >> 6;
  constexpr int CT = NW / 64;
  int cbase = w * (NW / 4);
  f32x4 acc[CT];
  #pragma unroll
  for (int ct = 0; ct < CT; ct++) acc[ct] = (f32x4)0.f;
  int rq = (lane >> 4) * 8;
  int arow = (lane & 15) * 40 + rq;

  // ---- phase A: chunks 0,1,2 -> global slabs 0..5 ----
  CST(c0, 0); CST(c1, 1); CST(c2, 2);
  __syncthreads();
  for (int kt = 0; kt < 6; kt++) {
    frag8 fah = *(const frag8*)&Ah[kt * 640 + arow];
    frag8 fal = *(const frag8*)&Al[kt * 640 + arow];
    frag8 fbh[CT], fbl[CT];
    #pragma unroll
    for (int ct = 0; ct < CT; ct++) {
      int c = cbase + ct * 16 + (lane & 15);
      fbh[ct] = *(const frag8*)&Wh[c * 384 + kt * 32 + rq];
      fbl[ct] = *(const frag8*)&Wl[c * 384 + kt * 32 + rq];
    }
    #pragma unroll
    for (int ct = 0; ct < CT; ct++) {
      acc[ct] = __builtin_amdgcn_mfma_f32_16x16x32_bf16(fah, fbh[ct], acc[ct], 0, 0, 0);
      acc[ct] = __builtin_amdgcn_mfma_f32_16x16x32_bf16(fal, fbh[ct], acc[ct], 0, 0, 0);
      acc[ct] = __builtin_amdgcn_mfma_f32_16x16x32_bf16(fah, fbl[ct], acc[ct], 0, 0, 0);
    }
  }
  __syncthreads();

  // ---- phase B: chunks 3,4,5 -> global slabs 6..11 (local 0..5) ----
  CST(c3, 0); CST(c4, 1); CST(c5, 2);
  #undef CST
  __syncthreads();
  for (int kt = 0; kt < 6; kt++) {
    int ktg = kt + 6;
    frag8 fah = *(const frag8*)&Ah[kt * 640 + arow];
    frag8 fal = *(const frag8*)&Al[kt * 640 + arow];
    frag8 fbh[CT], fbl[CT];
    #pragma unroll
    for (int ct = 0; ct < CT; ct++) {
      int c = cbase + ct * 16 + (lane & 15);
      fbh[ct] = *(const frag8*)&Wh[c * 384 + ktg * 32 + rq];
      fbl[ct] = *(const frag8*)&Wl[c * 384 + ktg * 32 + rq];
    }
    #pragma unroll
    for (int ct = 0; ct < CT; ct++) {
      acc[ct] = __builtin_amdgcn_mfma_f32_16x16x32_bf16(fah, fbh[ct], acc[ct], 0, 0, 0);
      acc[ct] = __builtin_amdgcn_mfma_f32_16x16x32_bf16(fal, fbh[ct], acc[ct], 0, 0, 0);
      acc[ct] = __builtin_amdgcn_mfma_f32_16x16x32_bf16(fah, fbl[ct], acc[ct], 0, 0, 0);
    }
  }

  // ---- epilogue: C/D layout col=lane&15, row=(lane>>4)*4+reg ----
  #pragma unroll
  for (int ct = 0; ct < CT; ct++) {
    #pragma unroll
    for (int g = 0; g < 4; g++) {
      int rr = (lane >> 4) * 4 + g;          // 0..15
      int gr2 = row0 + rr;
      int c = cbase + ct * 16 + (lane & 15);
      float v = acc[ct][g] + bias[c];
      if (MODE == 0) {
        float sg = 1.f / (1.f + __expf(-v));
        if (c >= ND) Ubuf[gr2 * ND + (c - ND)] = sg;
        else RH[gr2 * ND + c] = sg * h[gr2 * ND + c];
      } else {
        float cv = tanhf(v);
        float u = Ubuf[gr2 * ND + c];
        float ho = h[gr2 * ND + c];
        float hn = u * ho + (1.f - u) * cv;
        h[gr2 * ND + c] = hn;
      }
    }
  }
}

// out[b,q,n] = relu(h[n,b,:] @ W1 + b1) @ W2 + b2   (round-0-proven)
__global__ void k_out(const float* __restrict__ h, const float* __restrict__ W1,
                      const float* __restrict__ b1, const float* __restrict__ W2,
                      const float* __restrict__ b2, float* __restrict__ out, int q) {
  int row = blockIdx.x;            // n*64 + b
  int n = row >> 6, b = row & 63;
  int d = threadIdx.x;
  __shared__ float s[ND];
  s[d] = h[row * ND + d];
  __syncthreads();
  float acc = b1[d];
  #pragma unroll 8
  for (int k = 0; k < ND; k++) acc = fmaf(s[k], W1[k * ND + d], acc);
  acc = acc > 0.f ? acc : 0.f;
  float p = acc * W2[d];
  #pragma unroll
  for (int off = 32; off > 0; off >>= 1) p += __shfl_down(p, off);
  if (d == 0) out[(b * NQ + q) * NN + n] = p + b2[0];
}

extern "C" void kernel_launch(void* const* d_in, const int* in_sizes, int n_in,
                              void* d_out, int out_size, void* d_ws, size_t ws_size,
                              hipStream_t stream) {
  const float* X     = (const float*)d_in[0];
  const int*   TE    = (const int*)  d_in[1];
  const float* S0    = (const float*)d_in[2];
  const float* S1    = (const float*)d_in[3];
  const float* W_te1 = (const float*)d_in[4];
  const float* b_te1 = (const float*)d_in[5];
  const float* W_te2 = (const float*)d_in[6];
  const float* b_te2 = (const float*)d_in[7];
  const float* E_se  = (const float*)d_in[8];
  const float* W_in1 = (const float*)d_in[9];
  const float* b_in1 = (const float*)d_in[10];
  const float* W_in2 = (const float*)d_in[11];
  const float* b_in2 = (const float*)d_in[12];
  const float* enc_Wg = (const float*)d_in[13];
  const float* enc_bg = (const float*)d_in[14];
  const float* enc_Wc = (const float*)d_in[15];
  const float* enc_bc = (const float*)d_in[16];
  const float* dec_Wg = (const float*)d_in[17];
  const float* dec_bg = (const float*)d_in[18];
  const float* dec_Wc = (const float*)d_in[19];
  const float* dec_bc = (const float*)d_in[20];
  const float* W_out1 = (const float*)d_in[21];
  const float* b_out1 = (const float*)d_in[22];
  const float* W_out2 = (const float*)d_in[23];
  const float* b_out2 = (const float*)d_in[24];
  float* out = (float*)d_out;
  float* ws = (float*)d_ws;

  // workspace layout (floats) — ~23 MiB total
  float* te    = ws;                     // 98304
  float* h     = te    + 98304;          // 1331200
  float* RH    = h     + 1331200;        // 1331200
  float* U     = RH    + 1331200;        // 1331200
  float* embX  = U     + 1331200;        // 1331200 (one step slab)
  float* SE    = embX  + 1331200;        // 41600 (2*NN*ND)
  float* sumv  = SE    + 41600;          // 1024 (650 used)
  float* csrV  = sumv  + 1024;           // 41600
  int*   csrI  = (int*)(csrV + 41600);   // 41600 ints
  int*   csrC  = csrI + 41600;           // 1024 ints (650 used)
  unsigned short* wbuf = (unsigned short*)(csrC + 1024);  // 16B-aligned
  unsigned short* egWh = wbuf;                    // 128*384 each
  unsigned short* egWl = egWh + 49152;
  unsigned short* dgWh = egWl + 49152;
  unsigned short* dgWl = dgWh + 49152;
  unsigned short* ecWh = dgWl + 49152;            // 64*384 each
  unsigned short* ecWl = ecWh + 24576;
  unsigned short* dcWh = ecWl + 24576;
  unsigned short* dcWl = dcWh + 24576;

  k_te<<<NB * NT, ND, 0, stream>>>(TE, W_te1, b_te1, W_te2, b_te2, te);
  k_zero<<<(1331200 + 255) / 256, 256, 0, stream>>>(h, 1331200);
  k_csr<<<dim3(NN, 2), 64, 0, stream>>>(S0, S1, csrC, csrI, csrV);
  k_se<<<dim3(NN, 2), ND, 0, stream>>>(csrC, csrI, csrV, E_se, SE, sumv);
  k_convW<<<384, 128, 0, stream>>>(enc_Wg, egWh, egWl, 128);
  k_convW<<<384, 128, 0, stream>>>(dec_Wg, dgWh, dgWl, 128);
  k_convW<<<384,  64, 0, stream>>>(enc_Wc, ecWh, ecWl, 64);
  k_convW<<<384,  64, 0, stream>>>(dec_Wc, dcWh, dcWl, 64);

  const int GRID = 164 * 8;   // XCD-aligned decode, n>=NN guarded (1312)

  for (int t = 0; t < NT; t++) {
    int enc = (t < NP) ? 1 : 0;
    const unsigned short* Wgh = enc ? egWh : dgWh;
    const unsigned short* Wgl = enc ? egWl : dgWl;
    const unsigned short* Wch = enc ? ecWh : dcWh;
    const unsigned short* Wcl = enc ? ecWl : dcWl;
    const float* bg = enc ? enc_bg : dec_bg;
    const float* bc = enc ? enc_bc : dec_bc;

    if (enc)
      k_embX1<<<NR, ND, 0, stream>>>(X, W_in1, b_in1, W_in2, b_in2, embX, t);
    k_fused<128, 0><<<GRID, 256, 0, stream>>>(
        t, enc, te, E_se, embX, h, RH, U, SE, sumv,
        csrC, csrI, csrV, Wgh, Wgl, bg);
    k_fused<64, 1><<<GRID, 256, 0, stream>>>(
        t, enc, te, E_se, embX, h, RH, U, SE, sumv,
        csrC, csrI, csrV, Wch, Wcl, bc);
    if (!enc)
      k_out<<<NR, ND, 0, stream>>>(h, W_out1, b_out1, W_out2, b_out2, out, t - NP);
  }
}

// Round 9
// 1795.075 us; speedup vs baseline: 1.4094x; 1.4094x over previous
//
#include <hip/hip_runtime.h>
#include <math.h>

#define NB 64      // batch
#define NP 12      // encoder steps
#define NQ 12      // decoder steps
#define NT 24      // P+Q
#define NN 325     // nodes
#define ND 64      // units
#define NR 20800   // NN*NB rows
#define CAP 64     // max nnz per S row

typedef __attribute__((ext_vector_type(8))) short frag8;
typedef __attribute__((ext_vector_type(4))) float f32x4;

__device__ inline unsigned short f2bf(float f) {
  unsigned u = __builtin_bit_cast(unsigned, f);
  unsigned r = u + 0x7FFFu + ((u >> 16) & 1u);
  return (unsigned short)(r >> 16);
}
__device__ inline float bf2f(unsigned short h) {
  unsigned u = ((unsigned)h) << 16;
  return __builtin_bit_cast(float, u);
}

__global__ void k_te(const int* __restrict__ TE, const float* __restrict__ W1,
                     const float* __restrict__ b1, const float* __restrict__ W2,
                     const float* __restrict__ b2, float* __restrict__ te) {
  int row = blockIdx.x;            // b*24+t  (1536 rows)
  int d = threadIdx.x;
  __shared__ float s[ND];
  int wd = TE[row * 2 + 0], td = TE[row * 2 + 1];
  float v = W1[wd * ND + d] + W1[(7 + td) * ND + d] + b1[d];
  s[d] = v > 0.f ? v : 0.f;
  __syncthreads();
  float acc = b2[d];
  #pragma unroll 8
  for (int k = 0; k < ND; k++) acc = fmaf(s[k], W2[k * ND + d], acc);
  te[row * ND + d] = acc;
}

__global__ void k_zero(float* __restrict__ p, int n) {
  int i = blockIdx.x * 256 + threadIdx.x;
  if (i < n) p[i] = 0.f;
}

// W (384 x nw) fp32 -> FRAGMENT-MAJOR bf16 hi/lo.
// ushort index: (((T*12+kt)*4+q)*16+i)*8+e  with col=T*16+i, k=kt*32+q*8+e.
// A wave's frag load (q=lane>>4, i=lane&15) is then 1KB contiguous.
__global__ void k_convWp(const float* __restrict__ W, unsigned short* __restrict__ Wh,
                         unsigned short* __restrict__ Wl, int nw) {
  int k = blockIdx.x;              // 384
  int n = threadIdx.x;             // nw
  float w = W[k * nw + n];
  unsigned short h = f2bf(w);
  int T = n >> 4, i = n & 15;
  int kt = k >> 5, r = k & 31, q = r >> 3, e = r & 7;
  size_t idx = ((((size_t)T * 12 + kt) * 4 + q) * 16 + i) * 8 + e;
  Wh[idx] = h;
  Wl[idx] = f2bf(w - bf2f(h));
}

// CSR build for S0/S1; one wave per (row, support), ballot compaction.
__global__ void k_csr(const float* __restrict__ S0g, const float* __restrict__ S1g,
                      int* __restrict__ cnt, int* __restrict__ idx,
                      float* __restrict__ val) {
  int m = blockIdx.x, z = blockIdx.y;
  const float* S = z ? S1g : S0g;
  int lane = threadIdx.x;
  int c = 0;
  for (int k0 = 0; k0 < NN; k0 += 64) {
    int k = k0 + lane;
    float v = (k < NN) ? S[m * NN + k] : 0.f;
    bool p = (v != 0.f);
    unsigned long long mask = __ballot(p);
    int pos = c + __popcll(mask & ((1ull << lane) - 1ull));
    if (p) {
      idx[(z * NN + m) * CAP + pos] = k;
      val[(z * NN + m) * CAP + pos] = v;
    }
    c += __popcll(mask);
  }
  if (lane == 0) cnt[z * NN + m] = c;
}

// SE[z][m][d] = sum_j val*E_se[idx[j]][d];  sumv[z][m] = sum_j val
__global__ void k_se(const int* __restrict__ cnt, const int* __restrict__ idx,
                     const float* __restrict__ val, const float* __restrict__ E_se,
                     float* __restrict__ SE, float* __restrict__ sumv) {
  int m = blockIdx.x, z = blockIdx.y, d = threadIdx.x;
  int nz = cnt[z * NN + m];
  float acc = 0.f, sv = 0.f;
  for (int j = 0; j < nz; j++) {
    float v = val[(z * NN + m) * CAP + j];
    int jn = idx[(z * NN + m) * CAP + j];
    acc = fmaf(v, E_se[jn * ND + d], acc);
    sv += v;
  }
  SE[(z * NN + m) * ND + d] = acc;
  if (d == 0) sumv[z * NN + m] = sv;
}

// embX[n*64+b][d] = (relu(X*Wi1+bi1)@Wi2+bi2)[d] for one encoder step t
__global__ void k_embX1(const float* __restrict__ X, const float* __restrict__ Wi1,
                        const float* __restrict__ bi1, const float* __restrict__ Wi2,
                        const float* __restrict__ bi2, float* __restrict__ embX, int t) {
  int row = blockIdx.x; int n = row >> 6, b = row & 63; int d = threadIdx.x;
  __shared__ float s[ND];
  float x = X[(b * NP + t) * NN + n];
  float v = fmaf(x, Wi1[d], bi1[d]);
  s[d] = v > 0.f ? v : 0.f;
  __syncthreads();
  float acc = bi2[d];
  #pragma unroll 8
  for (int k = 0; k < ND; k++) acc = fmaf(s[k], Wi2[k * ND + d], acc);
  embX[row * ND + d] = acc;
}

// 4x-grouped neighbor gather: dst = sum_j sVal[z][j] * SRC[row(j)]
// (manual grouping for MLP — 4 outstanding loads; no pragmas)
#define GATH4(dst, SRC, z) do {                                               \
  int nz_ = sCnt[z];                                                          \
  f32x4 a0_ = (f32x4)0.f, a1_ = (f32x4)0.f, a2_ = (f32x4)0.f,                 \
        a3_ = (f32x4)0.f;                                                     \
  int j_ = 0;                                                                 \
  for (; j_ + 4 <= nz_; j_ += 4) {                                            \
    float v0_ = sVal[z][j_],     v1_ = sVal[z][j_ + 1];                       \
    float v2_ = sVal[z][j_ + 2], v3_ = sVal[z][j_ + 3];                       \
    int i0_ = sIdx[z][j_],     i1_ = sIdx[z][j_ + 1];                         \
    int i2_ = sIdx[z][j_ + 2], i3_ = sIdx[z][j_ + 3];                         \
    f32x4 g0_ = *(const f32x4*)&SRC[((size_t)(i0_ * 64 + b)) * ND + ko];      \
    f32x4 g1_ = *(const f32x4*)&SRC[((size_t)(i1_ * 64 + b)) * ND + ko];      \
    f32x4 g2_ = *(const f32x4*)&SRC[((size_t)(i2_ * 64 + b)) * ND + ko];      \
    f32x4 g3_ = *(const f32x4*)&SRC[((size_t)(i3_ * 64 + b)) * ND + ko];      \
    a0_ += v0_ * g0_; a1_ += v1_ * g1_; a2_ += v2_ * g2_; a3_ += v3_ * g3_;   \
  }                                                                           \
  for (; j_ < nz_; j_++) {                                                    \
    float v_ = sVal[z][j_]; int i_ = sIdx[z][j_];                             \
    a0_ += v_ * *(const f32x4*)&SRC[((size_t)(i_ * 64 + b)) * ND + ko];       \
  }                                                                           \
  dst = (a0_ + a1_) + (a2_ + a3_);                                            \
} while (0)

// Fused gconv: per block = 16-row panel (node n, batch-quarter bq).
// XCD-aligned decode (round-robin bid%8 -> XCD): bq = (bid&7)>>1.
// K-split 2-phase LDS (6 slabs, 16.4 KB). x-decomposition (exact):
// S@x = sv*te + SE (+ S@embX if enc); cand recomputes it (no SVx relay).
// B fragments from FRAGMENT-MAJOR packed weights (1KB/wave contiguous).
//  MODE 0 (gate, NW=128): sg=sigmoid; c<64 -> RH=sg*h; c>=64 -> U=sg.
//  MODE 1 (cand, NW=64): h = u*h + (1-u)*tanh(acc+b).
template<int NW, int MODE>
__global__ void __launch_bounds__(256, 6)
k_fused(int t, int enc,
        const float* __restrict__ te, const float* __restrict__ E_se,
        const float* __restrict__ embX,
        float* __restrict__ h, float* __restrict__ RH, float* __restrict__ Ubuf,
        const float* __restrict__ SE, const float* __restrict__ sumv,
        const int* __restrict__ cnt, const int* __restrict__ idx,
        const float* __restrict__ val,
        const unsigned short* __restrict__ Wh, const unsigned short* __restrict__ Wl,
        const float* __restrict__ bias) {
  int bid = blockIdx.x;
  int p8 = bid & 7;                // XCD id under round-robin dispatch
  int bq = p8 >> 1;                // batch-quarter pinned per XCD pair
  int n = (bid >> 3) * 2 + (p8 & 1);
  if (n >= NN) return;
  int row0 = n * 64 + bq * 16;
  int tid = threadIdx.x;

  __shared__ unsigned short Ah[6 * 16 * 40];   // 7680 B
  __shared__ unsigned short Al[6 * 16 * 40];   // 7680 B
  __shared__ int   sIdx[2][CAP];
  __shared__ float sVal[2][CAP];
  __shared__ int   sCnt[2];

  if (tid < 128) {
    int z = tid >> 6, l = tid & 63;
    sIdx[z][l] = idx[(z * NN + n) * CAP + l];
    sVal[z][l] = val[(z * NN + n) * CAP + l];
    if (l == 0) sCnt[z] = cnt[z * NN + n];
  }
  __syncthreads();

  int r = tid >> 4, kq = tid & 15;
  int b = bq * 16 + r;
  int grow = row0 + r;
  int ko = kq * 4;

  // ---- gather all six chunks (fp32 regs) ----
  f32x4 tev = *(const f32x4*)&te[(b * NT + t) * ND + ko];
  f32x4 c0 = tev + *(const f32x4*)&E_se[n * ND + ko];
  if (enc) c0 += *(const f32x4*)&embX[(size_t)grow * ND + ko];
  f32x4 c1, c2, c3, c4, c5;
  float sv0 = sumv[n], sv1 = sumv[NN + n];
  c2 = sv0 * tev + *(const f32x4*)&SE[n * ND + ko];
  c4 = sv1 * tev + *(const f32x4*)&SE[(NN + n) * ND + ko];
  if (enc) {
    f32x4 gx;
    GATH4(gx, embX, 0); c2 += gx;
    GATH4(gx, embX, 1); c4 += gx;
  }
  if (MODE == 0) {
    c1 = *(const f32x4*)&h[(size_t)grow * ND + ko];
    GATH4(c3, h, 0);
    GATH4(c5, h, 1);
  } else {
    c1 = *(const f32x4*)&RH[(size_t)grow * ND + ko];
    GATH4(c3, RH, 0);
    GATH4(c5, RH, 1);
  }

  // CST: local slab buffer (6 slabs). Chunk cc (local 0..2) covers
  // local slab 2cc+(kq>>3), row r, within-slab k (kq&7)*4.
  int r40 = r * 40;
  int sub = (kq >> 3) * 16 * 40 + (kq & 7) * 4;
  #define CST(vec, cc) do {                                                  \
    int _off = (cc) * 2 * 16 * 40 + sub + r40;                               \
    unsigned short h0 = f2bf(vec[0]), h1 = f2bf(vec[1]),                     \
                   h2 = f2bf(vec[2]), h3 = f2bf(vec[3]);                     \
    ushort4 hv = {h0, h1, h2, h3};                                           \
    ushort4 lv = {f2bf(vec[0] - bf2f(h0)), f2bf(vec[1] - bf2f(h1)),          \
                  f2bf(vec[2] - bf2f(h2)), f2bf(vec[3] - bf2f(h3))};         \
    *(ushort4*)&Ah[_off] = hv;                                               \
    *(ushort4*)&Al[_off] = lv;                                               \
  } while (0)

  int lane = tid & 63, w = tid >> 6;
  constexpr int CT = NW / 64;
  int cbase = w * (NW / 4);
  f32x4 acc[CT];
  #pragma unroll
  for (int ct = 0; ct < CT; ct++) acc[ct] = (f32x4)0.f;
  int rq = (lane >> 4) * 8;
  int arow = (lane & 15) * 40 + rq;
  // fragment-major W offset for this lane (ushort units), tile 0, kt 0:
  // (((T*12+kt)*4+q)*16+i)*8
  size_t wfl = (((size_t)(lane >> 4)) * 16 + (lane & 15)) * 8;

  // ---- phase A: chunks 0,1,2 -> global slabs 0..5 ----
  CST(c0, 0); CST(c1, 1); CST(c2, 2);
  __syncthreads();
  for (int kt = 0; kt < 6; kt++) {
    frag8 fah = *(const frag8*)&Ah[kt * 640 + arow];
    frag8 fal = *(const frag8*)&Al[kt * 640 + arow];
    frag8 fbh[CT], fbl[CT];
    #pragma unroll
    for (int ct = 0; ct < CT; ct++) {
      int tile = (cbase >> 4) + ct;
      size_t o = ((size_t)(tile * 12 + kt)) * 512 + wfl;
      fbh[ct] = *(const frag8*)&Wh[o];
      fbl[ct] = *(const frag8*)&Wl[o];
    }
    #pragma unroll
    for (int ct = 0; ct < CT; ct++) {
      acc[ct] = __builtin_amdgcn_mfma_f32_16x16x32_bf16(fah, fbh[ct], acc[ct], 0, 0, 0);
      acc[ct] = __builtin_amdgcn_mfma_f32_16x16x32_bf16(fal, fbh[ct], acc[ct], 0, 0, 0);
      acc[ct] = __builtin_amdgcn_mfma_f32_16x16x32_bf16(fah, fbl[ct], acc[ct], 0, 0, 0);
    }
  }
  __syncthreads();

  // ---- phase B: chunks 3,4,5 -> global slabs 6..11 (local 0..5) ----
  CST(c3, 0); CST(c4, 1); CST(c5, 2);
  #undef CST
  __syncthreads();
  for (int kt = 0; kt < 6; kt++) {
    int ktg = kt + 6;
    frag8 fah = *(const frag8*)&Ah[kt * 640 + arow];
    frag8 fal = *(const frag8*)&Al[kt * 640 + arow];
    frag8 fbh[CT], fbl[CT];
    #pragma unroll
    for (int ct = 0; ct < CT; ct++) {
      int tile = (cbase >> 4) + ct;
      size_t o = ((size_t)(tile * 12 + ktg)) * 512 + wfl;
      fbh[ct] = *(const frag8*)&Wh[o];
      fbl[ct] = *(const frag8*)&Wl[o];
    }
    #pragma unroll
    for (int ct = 0; ct < CT; ct++) {
      acc[ct] = __builtin_amdgcn_mfma_f32_16x16x32_bf16(fah, fbh[ct], acc[ct], 0, 0, 0);
      acc[ct] = __builtin_amdgcn_mfma_f32_16x16x32_bf16(fal, fbh[ct], acc[ct], 0, 0, 0);
      acc[ct] = __builtin_amdgcn_mfma_f32_16x16x32_bf16(fah, fbl[ct], acc[ct], 0, 0, 0);
    }
  }

  // ---- epilogue: C/D layout col=lane&15, row=(lane>>4)*4+reg ----
  #pragma unroll
  for (int ct = 0; ct < CT; ct++) {
    #pragma unroll
    for (int g = 0; g < 4; g++) {
      int rr = (lane >> 4) * 4 + g;          // 0..15
      int gr2 = row0 + rr;
      int c = cbase + ct * 16 + (lane & 15);
      float v = acc[ct][g] + bias[c];
      if (MODE == 0) {
        float sg = 1.f / (1.f + __expf(-v));
        if (c >= ND) Ubuf[gr2 * ND + (c - ND)] = sg;
        else RH[gr2 * ND + c] = sg * h[gr2 * ND + c];
      } else {
        float cv = tanhf(v);
        float u = Ubuf[gr2 * ND + c];
        float ho = h[gr2 * ND + c];
        float hn = u * ho + (1.f - u) * cv;
        h[gr2 * ND + c] = hn;
      }
    }
  }
}

// out[b,q,n] = relu(h[n,b,:] @ W1 + b1) @ W2 + b2   (round-0-proven)
__global__ void k_out(const float* __restrict__ h, const float* __restrict__ W1,
                      const float* __restrict__ b1, const float* __restrict__ W2,
                      const float* __restrict__ b2, float* __restrict__ out, int q) {
  int row = blockIdx.x;            // n*64 + b
  int n = row >> 6, b = row & 63;
  int d = threadIdx.x;
  __shared__ float s[ND];
  s[d] = h[row * ND + d];
  __syncthreads();
  float acc = b1[d];
  #pragma unroll 8
  for (int k = 0; k < ND; k++) acc = fmaf(s[k], W1[k * ND + d], acc);
  acc = acc > 0.f ? acc : 0.f;
  float p = acc * W2[d];
  #pragma unroll
  for (int off = 32; off > 0; off >>= 1) p += __shfl_down(p, off);
  if (d == 0) out[(b * NQ + q) * NN + n] = p + b2[0];
}

extern "C" void kernel_launch(void* const* d_in, const int* in_sizes, int n_in,
                              void* d_out, int out_size, void* d_ws, size_t ws_size,
                              hipStream_t stream) {
  const float* X     = (const float*)d_in[0];
  const int*   TE    = (const int*)  d_in[1];
  const float* S0    = (const float*)d_in[2];
  const float* S1    = (const float*)d_in[3];
  const float* W_te1 = (const float*)d_in[4];
  const float* b_te1 = (const float*)d_in[5];
  const float* W_te2 = (const float*)d_in[6];
  const float* b_te2 = (const float*)d_in[7];
  const float* E_se  = (const float*)d_in[8];
  const float* W_in1 = (const float*)d_in[9];
  const float* b_in1 = (const float*)d_in[10];
  const float* W_in2 = (const float*)d_in[11];
  const float* b_in2 = (const float*)d_in[12];
  const float* enc_Wg = (const float*)d_in[13];
  const float* enc_bg = (const float*)d_in[14];
  const float* enc_Wc = (const float*)d_in[15];
  const float* enc_bc = (const float*)d_in[16];
  const float* dec_Wg = (const float*)d_in[17];
  const float* dec_bg = (const float*)d_in[18];
  const float* dec_Wc = (const float*)d_in[19];
  const float* dec_bc = (const float*)d_in[20];
  const float* W_out1 = (const float*)d_in[21];
  const float* b_out1 = (const float*)d_in[22];
  const float* W_out2 = (const float*)d_in[23];
  const float* b_out2 = (const float*)d_in[24];
  float* out = (float*)d_out;
  float* ws = (float*)d_ws;

  // workspace layout (floats) — ~23 MiB total
  float* te    = ws;                     // 98304
  float* h     = te    + 98304;          // 1331200
  float* RH    = h     + 1331200;        // 1331200
  float* U     = RH    + 1331200;        // 1331200
  float* embX  = U     + 1331200;        // 1331200 (one step slab)
  float* SE    = embX  + 1331200;        // 41600 (2*NN*ND)
  float* sumv  = SE    + 41600;          // 1024 (650 used)
  float* csrV  = sumv  + 1024;           // 41600
  int*   csrI  = (int*)(csrV + 41600);   // 41600 ints
  int*   csrC  = csrI + 41600;           // 1024 ints (650 used)
  unsigned short* wbuf = (unsigned short*)(csrC + 1024);  // 16B-aligned
  unsigned short* egWh = wbuf;                    // 128*384 each
  unsigned short* egWl = egWh + 49152;
  unsigned short* dgWh = egWl + 49152;
  unsigned short* dgWl = dgWh + 49152;
  unsigned short* ecWh = dgWl + 49152;            // 64*384 each
  unsigned short* ecWl = ecWh + 24576;
  unsigned short* dcWh = ecWl + 24576;
  unsigned short* dcWl = dcWh + 24576;

  k_te<<<NB * NT, ND, 0, stream>>>(TE, W_te1, b_te1, W_te2, b_te2, te);
  k_zero<<<(1331200 + 255) / 256, 256, 0, stream>>>(h, 1331200);
  k_csr<<<dim3(NN, 2), 64, 0, stream>>>(S0, S1, csrC, csrI, csrV);
  k_se<<<dim3(NN, 2), ND, 0, stream>>>(csrC, csrI, csrV, E_se, SE, sumv);
  k_convWp<<<384, 128, 0, stream>>>(enc_Wg, egWh, egWl, 128);
  k_convWp<<<384, 128, 0, stream>>>(dec_Wg, dgWh, dgWl, 128);
  k_convWp<<<384,  64, 0, stream>>>(enc_Wc, ecWh, ecWl, 64);
  k_convWp<<<384,  64, 0, stream>>>(dec_Wc, dcWh, dcWl, 64);

  const int GRID = 164 * 8;   // XCD-aligned decode, n>=NN guarded (1312)

  for (int t = 0; t < NT; t++) {
    int enc = (t < NP) ? 1 : 0;
    const unsigned short* Wgh = enc ? egWh : dgWh;
    const unsigned short* Wgl = enc ? egWl : dgWl;
    const unsigned short* Wch = enc ? ecWh : dcWh;
    const unsigned short* Wcl = enc ? ecWl : dcWl;
    const float* bg = enc ? enc_bg : dec_bg;
    const float* bc = enc ? enc_bc : dec_bc;

    if (enc)
      k_embX1<<<NR, ND, 0, stream>>>(X, W_in1, b_in1, W_in2, b_in2, embX, t);
    k_fused<128, 0><<<GRID, 256, 0, stream>>>(
        t, enc, te, E_se, embX, h, RH, U, SE, sumv,
        csrC, csrI, csrV, Wgh, Wgl, bg);
    k_fused<64, 1><<<GRID, 256, 0, stream>>>(
        t, enc, te, E_se, embX, h, RH, U, SE, sumv,
        csrC, csrI, csrV, Wch, Wcl, bc);
    if (!enc)
      k_out<<<NR, ND, 0, stream>>>(h, W_out1, b_out1, W_out2, b_out2, out, t - NP);
  }
}